// Round 5
// baseline (514.375 us; speedup 1.0000x reference)
//
#include <hip/hip_runtime.h>
#include <math.h>

#define NFEAT 128
#define F1    30   // conv1 out features
#define F1P   32   // padded width for conv1 tables
#define F2    20   // conv2 out features

#define EPB     8192   // edges per block in CSR-build passes
#define MAXBUCK 1024   // LDS sizing; NBUCK = ceil(n/128) must be <= this

// ------- prep: Wp[table][k][j] padded 128x32, table 0=rel, 1=root --------------
__global__ __launch_bounds__(256) void k_prepw(
    const float* __restrict__ Wrel, const float* __restrict__ Wroot,
    float* __restrict__ Wp)
{
    int i = blockIdx.x * 256 + threadIdx.x;
    if (i >= 2 * 128 * 32) return;
    int table = i >> 12, rem = i & 4095, k = rem >> 5, j = rem & 31;
    const float* W = table ? Wroot : Wrel;
    Wp[i] = (j < F1) ? W[k * F1 + j] : 0.f;
}

// ------- k_proj1: thread = (node, table, j-quad). 8 acc regs, 800K threads -----
__global__ __launch_bounds__(256) void k_proj1(
    const float* __restrict__ x, const float* __restrict__ Wp,
    float* __restrict__ y1, float* __restrict__ r1, int n)
{
    int idx = blockIdx.x * 256 + threadIdx.x;
    int node = idx >> 3, v = idx & 7;
    if (node >= n) return;
    int table = v >> 2, q = v & 3;
    const float* Wt = Wp + table * 4096 + q * 8;
    const float4* xv = (const float4*)(x + (size_t)node * NFEAT);
    float acc[8];
#pragma unroll
    for (int j = 0; j < 8; j++) acc[j] = 0.f;
    for (int k4 = 0; k4 < 32; k4++) {
        float4 xk = xv[k4];
#pragma unroll
        for (int kk = 0; kk < 4; kk++) {
            float xs = kk == 0 ? xk.x : kk == 1 ? xk.y : kk == 2 ? xk.z : xk.w;
            const float4* w = (const float4*)(Wt + (k4 * 4 + kk) * 32);
            float4 w0 = w[0], w1 = w[1];
            acc[0] += xs * w0.x; acc[1] += xs * w0.y;
            acc[2] += xs * w0.z; acc[3] += xs * w0.w;
            acc[4] += xs * w1.x; acc[5] += xs * w1.y;
            acc[6] += xs * w1.z; acc[7] += xs * w1.w;
        }
    }
    float* outp = (table ? r1 : y1) + (size_t)node * F1P + q * 8;
    ((float4*)outp)[0] = make_float4(acc[0], acc[1], acc[2], acc[3]);
    ((float4*)outp)[1] = make_float4(acc[4], acc[5], acc[6], acc[7]);
}

// ============ CSR build: hierarchical counting sort, no global atomics ==========
// p1: per-block LDS histogram over buckets (bucket = dst >> 7)
__global__ __launch_bounds__(256) void k_p1(
    const int* __restrict__ ei, int* __restrict__ blockCnt,
    int E, int nbuck)
{
    __shared__ int lh[MAXBUCK];
    int t = threadIdx.x;
    for (int i = t; i < nbuck; i += 256) lh[i] = 0;
    __syncthreads();
    const int* dst = ei + E;
    int base = blockIdx.x * EPB;
#pragma unroll 4
    for (int k = 0; k < EPB / 256; k++) {
        int e = base + k * 256 + t;
        if (e < E) atomicAdd(&lh[dst[e] >> 7], 1);
    }
    __syncthreads();
    int* out = blockCnt + (size_t)blockIdx.x * nbuck;
    for (int i = t; i < nbuck; i += 256) out[i] = lh[i];
}

// p2: per-bucket exclusive scan across edge-blocks (one workgroup per bucket)
__global__ __launch_bounds__(256) void k_p2(
    const int* __restrict__ blockCnt, int* __restrict__ blockOff,
    int* __restrict__ bucketTot, int neb, int nbuck)
{
    __shared__ int sdata[256];
    __shared__ int carry_s;
    int b = blockIdx.x;
    int t = threadIdx.x;
    if (t == 0) carry_s = 0;
    __syncthreads();
    for (int base = 0; base < neb; base += 512) {
        int i0 = base + 2 * t, i1 = i0 + 1;
        int c0 = (i0 < neb) ? blockCnt[(size_t)i0 * nbuck + b] : 0;
        int c1 = (i1 < neb) ? blockCnt[(size_t)i1 * nbuck + b] : 0;
        int s = c0 + c1;
        sdata[t] = s;
        __syncthreads();
        for (int off = 1; off < 256; off <<= 1) {
            int tmp = (t >= off) ? sdata[t - off] : 0;
            __syncthreads();
            sdata[t] += tmp;
            __syncthreads();
        }
        int ex = carry_s + sdata[t] - s;
        if (i0 < neb) blockOff[(size_t)i0 * nbuck + b] = ex;
        if (i1 < neb) blockOff[(size_t)i1 * nbuck + b] = ex + c0;
        __syncthreads();
        if (t == 255) carry_s += sdata[255];
        __syncthreads();
    }
    if (t == 0) bucketTot[b] = carry_s;
}

// p3: single-block parallel exclusive scan over bucket totals
__global__ __launch_bounds__(256) void k_p3(
    const int* __restrict__ bucketTot, int* __restrict__ bucketStart, int nbuck)
{
    __shared__ int sdata[256];
    __shared__ int carry_s;
    int t = threadIdx.x;
    if (t == 0) carry_s = 0;
    __syncthreads();
    for (int base = 0; base < nbuck; base += 1024) {
        int v[4]; int s = 0;
#pragma unroll
        for (int i = 0; i < 4; i++) {
            int idx = base + t * 4 + i;
            v[i] = (idx < nbuck) ? bucketTot[idx] : 0;
            s += v[i];
        }
        sdata[t] = s;
        __syncthreads();
        for (int off = 1; off < 256; off <<= 1) {
            int tmp = (t >= off) ? sdata[t - off] : 0;
            __syncthreads();
            sdata[t] += tmp;
            __syncthreads();
        }
        int ex = carry_s + sdata[t] - s;
#pragma unroll
        for (int i = 0; i < 4; i++) {
            int idx = base + t * 4 + i;
            if (idx < nbuck) bucketStart[idx] = ex;
            ex += v[i];
        }
        __syncthreads();
        if (t == 255) carry_s += sdata[255];
        __syncthreads();
    }
    if (t == 0) bucketStart[nbuck] = carry_s;
}

// p4: scatter edges into bucket-sorted packed (src<<7 | dst&127) via LDS cursors
__global__ __launch_bounds__(256) void k_p4(
    const int* __restrict__ ei, const int* __restrict__ bucketStart,
    const int* __restrict__ blockOff, int* __restrict__ ebuf,
    int E, int nbuck)
{
    __shared__ int cur[MAXBUCK];
    int t = threadIdx.x;
    const int* boff = blockOff + (size_t)blockIdx.x * nbuck;
    for (int i = t; i < nbuck; i += 256) cur[i] = bucketStart[i] + boff[i];
    __syncthreads();
    const int* dst = ei + E;
    int base = blockIdx.x * EPB;
#pragma unroll 4
    for (int k = 0; k < EPB / 256; k++) {
        int e = base + k * 256 + t;
        if (e < E) {
            int s = ei[e], d = dst[e];
            int p = atomicAdd(&cur[d >> 7], 1);
            ebuf[p] = (s << 7) | (d & 127);
        }
    }
}

// p5: per-bucket 128-bin node histogram -> deg (plain stores, no atomics)
__global__ __launch_bounds__(256) void k_p5(
    const int* __restrict__ ebuf, const int* __restrict__ bucketStart,
    int* __restrict__ deg, int n)
{
    __shared__ int nh[128];
    int t = threadIdx.x;
    int b = blockIdx.x;
    if (t < 128) nh[t] = 0;
    __syncthreads();
    int lo = bucketStart[b], hi = bucketStart[b + 1];
    for (int p = lo + t; p < hi; p += 256)
        atomicAdd(&nh[ebuf[p] & 127], 1);
    __syncthreads();
    if (t < 128) {
        int node = b * 128 + t;
        if (node < n) deg[node] = nh[t];
    }
}

// scan over deg -> rowstart (3 kernels, 1024-elt chunks)
__global__ __launch_bounds__(256) void k_scan1(
    const int* __restrict__ deg, int* __restrict__ bsum, int n)
{
    __shared__ int sdata[256];
    int t = threadIdx.x;
    int base = blockIdx.x * 1024;
    int s = 0;
#pragma unroll
    for (int i = 0; i < 4; i++) {
        int idx = base + t * 4 + i;
        if (idx < n) s += deg[idx];
    }
    sdata[t] = s;
    __syncthreads();
    for (int off = 128; off > 0; off >>= 1) {
        if (t < off) sdata[t] += sdata[t + off];
        __syncthreads();
    }
    if (t == 0) bsum[blockIdx.x] = sdata[0];
}

__global__ void k_scan2(const int* __restrict__ bsum, int* __restrict__ boff, int nb)
{
    if (threadIdx.x == 0 && blockIdx.x == 0) {
        int acc = 0;
        for (int i = 0; i < nb; i++) { boff[i] = acc; acc += bsum[i]; }
    }
}

__global__ __launch_bounds__(256) void k_scan3(
    const int* __restrict__ deg, const int* __restrict__ boff,
    int* __restrict__ rowstart, int n)
{
    __shared__ int sdata[256];
    int t = threadIdx.x;
    int base = blockIdx.x * 1024;
    int v[4]; int s = 0;
#pragma unroll
    for (int i = 0; i < 4; i++) {
        int idx = base + t * 4 + i;
        v[i] = (idx < n) ? deg[idx] : 0;
        s += v[i];
    }
    sdata[t] = s;
    __syncthreads();
    for (int off = 1; off < 256; off <<= 1) {
        int tmp = (t >= off) ? sdata[t - off] : 0;
        __syncthreads();
        sdata[t] += tmp;
        __syncthreads();
    }
    int ex = boff[blockIdx.x] + sdata[t] - s;
#pragma unroll
    for (int i = 0; i < 4; i++) {
        int idx = base + t * 4 + i;
        if (idx < n) rowstart[idx] = ex;
        ex += v[i];
    }
}

// p6: per-bucket scatter into perm, src-QUARTILE ordered within each node's list
__global__ __launch_bounds__(256) void k_p6(
    const int* __restrict__ ebuf, const int* __restrict__ bucketStart,
    const int* __restrict__ rowstart, int* __restrict__ perm, int n,
    int t1, int t2, int t3)
{
    __shared__ int cur[128];
    int t = threadIdx.x;
    int b = blockIdx.x;
    if (t < 128) {
        int node = b * 128 + t;
        cur[t] = (node < n) ? rowstart[node] : 0;
    }
    __syncthreads();
    int lo = bucketStart[b], hi = bucketStart[b + 1];
    for (int pass = 0; pass < 4; pass++) {
        for (int p = lo + t; p < hi; p += 256) {
            int e = ebuf[p];
            int src = e >> 7;
            int qq = (src >= t1) + (src >= t2) + (src >= t3);
            if (qq == pass) {
                int q = atomicAdd(&cur[e & 127], 1);
                perm[q] = src;
            }
        }
        __syncthreads();   // phase coherence across the block
    }
}

// ---------------- gather-sum aggregations (no atomics, unroll-4) ----------------
__global__ __launch_bounds__(256) void k_agg1(
    const int* __restrict__ rowstart, const int* __restrict__ deg,
    const int* __restrict__ perm, const float* __restrict__ y1,
    float* __restrict__ agg1, int n)
{
    int idx = blockIdx.x * 256 + threadIdx.x;
    int node = idx >> 3, q = idx & 7;
    if (node >= n) return;
    int s = rowstart[node], e = s + deg[node];
    float4 acc = {0.f, 0.f, 0.f, 0.f};
    int j = s;
    for (; j + 4 <= e; j += 4) {
        int s0 = perm[j], s1 = perm[j + 1], s2 = perm[j + 2], s3 = perm[j + 3];
        float4 v0 = *(const float4*)(y1 + (size_t)s0 * F1P + q * 4);
        float4 v1 = *(const float4*)(y1 + (size_t)s1 * F1P + q * 4);
        float4 v2 = *(const float4*)(y1 + (size_t)s2 * F1P + q * 4);
        float4 v3 = *(const float4*)(y1 + (size_t)s3 * F1P + q * 4);
        acc.x += v0.x; acc.y += v0.y; acc.z += v0.z; acc.w += v0.w;
        acc.x += v1.x; acc.y += v1.y; acc.z += v1.z; acc.w += v1.w;
        acc.x += v2.x; acc.y += v2.y; acc.z += v2.z; acc.w += v2.w;
        acc.x += v3.x; acc.y += v3.y; acc.z += v3.z; acc.w += v3.w;
    }
    for (; j < e; j++) {
        int sr = perm[j];
        float4 v = *(const float4*)(y1 + (size_t)sr * F1P + q * 4);
        acc.x += v.x; acc.y += v.y; acc.z += v.z; acc.w += v.w;
    }
    *(float4*)(agg1 + (size_t)node * F1P + q * 4) = acc;
}

__global__ __launch_bounds__(256) void k_agg2(
    const int* __restrict__ rowstart, const int* __restrict__ deg,
    const int* __restrict__ perm, const float* __restrict__ y2,
    float* __restrict__ agg2, int n)
{
    int idx = blockIdx.x * 256 + threadIdx.x;
    int node = idx / 5, q = idx - node * 5;
    if (node >= n) return;
    int s = rowstart[node], e = s + deg[node];
    float4 acc = {0.f, 0.f, 0.f, 0.f};
    int j = s;
    for (; j + 4 <= e; j += 4) {
        int s0 = perm[j], s1 = perm[j + 1], s2 = perm[j + 2], s3 = perm[j + 3];
        float4 v0 = *(const float4*)(y2 + (size_t)s0 * F2 + q * 4);
        float4 v1 = *(const float4*)(y2 + (size_t)s1 * F2 + q * 4);
        float4 v2 = *(const float4*)(y2 + (size_t)s2 * F2 + q * 4);
        float4 v3 = *(const float4*)(y2 + (size_t)s3 * F2 + q * 4);
        acc.x += v0.x; acc.y += v0.y; acc.z += v0.z; acc.w += v0.w;
        acc.x += v1.x; acc.y += v1.y; acc.z += v1.z; acc.w += v1.w;
        acc.x += v2.x; acc.y += v2.y; acc.z += v2.z; acc.w += v2.w;
        acc.x += v3.x; acc.y += v3.y; acc.z += v3.z; acc.w += v3.w;
    }
    for (; j < e; j++) {
        int sr = perm[j];
        float4 v = *(const float4*)(y2 + (size_t)sr * F2 + q * 4);
        acc.x += v.x; acc.y += v.y; acc.z += v.z; acc.w += v.w;
    }
    *(float4*)(agg2 + (size_t)node * F2 + q * 4) = acc;
}

// ---------------- k_mid: h = bn1(relu(agg1+r1+b1)); y2=h@Wrel2; r2=h@Wroot2+b2 --
__global__ __launch_bounds__(256) void k_mid(
    const float* __restrict__ agg1, const float* __restrict__ r1,
    const float* __restrict__ b1,
    const float* __restrict__ g1, const float* __restrict__ bb1,
    const float* __restrict__ m1, const float* __restrict__ v1,
    const float* __restrict__ Wrel2, const float* __restrict__ Wroot2,
    const float* __restrict__ b2,
    float* __restrict__ y2, float* __restrict__ r2, int n)
{
    int node = blockIdx.x * 256 + threadIdx.x;
    if (node >= n) return;
    float h[F1];
    const float4* av = (const float4*)(agg1 + (size_t)node * F1P);
    const float4* rv = (const float4*)(r1   + (size_t)node * F1P);
#pragma unroll
    for (int q = 0; q < 8; q++) {
        float4 a = av[q], r = rv[q];
        int j = q * 4;
        if (j + 0 < F1) h[j + 0] = a.x + r.x;
        if (j + 1 < F1) h[j + 1] = a.y + r.y;
        if (j + 2 < F1) h[j + 2] = a.z + r.z;
        if (j + 3 < F1) h[j + 3] = a.w + r.w;
    }
#pragma unroll
    for (int j = 0; j < F1; j++) {
        float t = fmaxf(h[j] + b1[j], 0.f);
        float sc = g1[j] / sqrtf(v1[j] + 1e-5f);
        h[j] = (t - m1[j]) * sc + bb1[j];
    }
    float ay[F2], ar[F2];
#pragma unroll
    for (int j = 0; j < F2; j++) { ay[j] = 0.f; ar[j] = b2[j]; }
    for (int k = 0; k < F1; k++) {
        float hk = h[k];
#pragma unroll
        for (int j = 0; j < F2; j++) {
            ay[j] += hk * Wrel2 [k * F2 + j];
            ar[j] += hk * Wroot2[k * F2 + j];
        }
    }
    float4* yo = (float4*)(y2 + (size_t)node * F2);
    float4* ro = (float4*)(r2 + (size_t)node * F2);
#pragma unroll
    for (int q = 0; q < 5; q++) {
        float4 vy, vr;
        vy.x = ay[q*4+0]; vy.y = ay[q*4+1]; vy.z = ay[q*4+2]; vy.w = ay[q*4+3];
        vr.x = ar[q*4+0]; vr.y = ar[q*4+1]; vr.z = ar[q*4+2]; vr.w = ar[q*4+3];
        yo[q] = vy;  ro[q] = vr;
    }
}

// ------------- k_pool: segmented (batch sorted) pool, flush-on-change -----------
__global__ __launch_bounds__(256) void k_pool(
    const float* __restrict__ agg2, const float* __restrict__ r2,
    const int* __restrict__ batch,
    const float* __restrict__ g2, const float* __restrict__ bb2,
    const float* __restrict__ m2, const float* __restrict__ v2,
    unsigned* __restrict__ gmaxU, float* __restrict__ gsum,
    int* __restrict__ cnt, int n)
{
    int t = threadIdx.x;
    if (t >= 240) return;                 // 12 subsets x 20 features
    int i = t / 20, j = t - (t / 20) * 20;
    int base = blockIdx.x * 256;
    int nend = min(base + 256, n);
    float sc = g2[j] / sqrtf(v2[j] + 1e-5f);
    float mj = m2[j], bj = bb2[j];

    int curg = -1, c = 0;
    float mx = -3.4e38f, sm = 0.f;
    for (int node = base + i; node < nend; node += 12) {
        int g = batch[node];
        if (g != curg) {
            if (curg >= 0) {
                atomicAdd(&gsum[curg * F2 + j], sm);
                unsigned bits = __float_as_uint(mx);
                unsigned mapped = (bits & 0x80000000u) ? ~bits : (bits | 0x80000000u);
                atomicMax(&gmaxU[curg * F2 + j], mapped);
                if (j == 0) atomicAdd(&cnt[curg], c);
            }
            curg = g; c = 0; mx = -3.4e38f; sm = 0.f;
        }
        float a = agg2[(size_t)node * F2 + j] + r2[(size_t)node * F2 + j];
        a = fmaxf(a, 0.f);                 // b2 folded into r2
        float h2 = (a - mj) * sc + bj;
        mx = fmaxf(mx, h2); sm += h2; c++;
    }
    if (curg >= 0) {
        atomicAdd(&gsum[curg * F2 + j], sm);
        unsigned bits = __float_as_uint(mx);
        unsigned mapped = (bits & 0x80000000u) ? ~bits : (bits | 0x80000000u);
        atomicMax(&gmaxU[curg * F2 + j], mapped);
        if (j == 0) atomicAdd(&cnt[curg], c);
    }
}

// ---------------- Kernel F: head MLP + sigmoid ---------------------------------
__global__ __launch_bounds__(256) void k_head(
    const unsigned* __restrict__ gmaxU, const float* __restrict__ gsum,
    const int* __restrict__ cnt,
    const float* __restrict__ W1, const float* __restrict__ b1h,
    const float* __restrict__ W2, const float* __restrict__ b2h,
    float* __restrict__ out, int G)
{
    int g = blockIdx.x * 256 + threadIdx.x;
    if (g >= G) return;
    int c = cnt[g];
    float cf = fmaxf((float)c, 1.f);
    float z[2 * F2];
#pragma unroll
    for (int j = 0; j < F2; j++) {
        unsigned u = gmaxU[g * F2 + j];
        float gm = 0.f;
        if (c != 0) {
            gm = (u & 0x80000000u) ? __uint_as_float(u & 0x7FFFFFFFu)
                                   : __uint_as_float(~u);
            if (!isfinite(gm)) gm = 0.f;
        }
        z[j]      = gm;
        z[F2 + j] = gsum[g * F2 + j] / cf;
    }
    float a[10];
#pragma unroll
    for (int i = 0; i < 10; i++) a[i] = b1h[i];
    for (int k = 0; k < 2 * F2; k++) {
        float zk = z[k];
#pragma unroll
        for (int i = 0; i < 10; i++) a[i] += zk * W1[k * 10 + i];
    }
    float o = b2h[0];
#pragma unroll
    for (int i = 0; i < 10; i++) o += fmaxf(a[i], 0.f) * W2[i];
    out[g] = 1.f / (1.f + expf(-o));
}

// ---------------- launch --------------------------------------------------------
extern "C" void kernel_launch(void* const* d_in, const int* in_sizes, int n_in,
                              void* d_out, int out_size, void* d_ws, size_t ws_size,
                              hipStream_t stream)
{
    const float* x      = (const float*)d_in[0];
    const int*   ei     = (const int*)  d_in[1];
    const int*   batch  = (const int*)  d_in[2];
    const float* Wrel1  = (const float*)d_in[3];
    const float* Wroot1 = (const float*)d_in[4];
    const float* b1     = (const float*)d_in[5];
    const float* bn1_g  = (const float*)d_in[6];
    const float* bn1_b  = (const float*)d_in[7];
    const float* bn1_m  = (const float*)d_in[8];
    const float* bn1_v  = (const float*)d_in[9];
    const float* Wrel2  = (const float*)d_in[10];
    const float* Wroot2 = (const float*)d_in[11];
    const float* b2     = (const float*)d_in[12];
    const float* bn2_g  = (const float*)d_in[13];
    const float* bn2_b  = (const float*)d_in[14];
    const float* bn2_m  = (const float*)d_in[15];
    const float* bn2_v  = (const float*)d_in[16];
    const float* W_lin1 = (const float*)d_in[17];
    const float* b_lin1 = (const float*)d_in[18];
    const float* W_lin2 = (const float*)d_in[19];
    const float* b_lin2 = (const float*)d_in[20];
    float* out = (float*)d_out;

    int n = in_sizes[0] / NFEAT;     // 100000
    int E = in_sizes[1] / 2;         // 3200000
    int G = out_size;                // 512
    int nb = (n + 1023) / 1024;      // scan chunks over nodes
    int nbuck = (n + 127) >> 7;      // 782 buckets of 128 nodes
    int neb = (E + EPB - 1) / EPB;   // 391 edge blocks
    int qs = (n + 3) >> 2;           // src quartile size

    char* p = (char*)d_ws;
    float* y1   = (float*)p;  p += (size_t)n * F1P * 4;   // 12.8 MB
    float* r1   = (float*)p;  p += (size_t)n * F1P * 4;   // 12.8 MB
    char* alias0 = p;                                     // start of aliased region
    float* agg1 = (float*)p;  p += (size_t)n * F1P * 4;   // 12.8 MB
    float* y2   = (float*)p;  p += (size_t)n * F2 * 4;    // 8 MB
    float* r2   = (float*)p;  p += (size_t)n * F2 * 4;    // 8 MB
    char* alias1 = p;                                     // start of 2nd alias region
    float* agg2 = (float*)p;  p += (size_t)n * F2 * 4;    // 8 MB
    unsigned* gmaxU = (unsigned*)p;  p += (size_t)G * F2 * 4;
    float*    gsum  = (float*)p;     p += (size_t)G * F2 * 4;
    int*      cnt   = (int*)p;       p += (size_t)G * 4;
    int* deg      = (int*)p;  p += (size_t)n * 4;
    int* rowstart = (int*)p;  p += (size_t)n * 4;
    int* bsum     = (int*)p;  p += (size_t)nb * 4;
    int* boff     = (int*)p;  p += (size_t)nb * 4;
    int* perm     = (int*)p;  p += (size_t)E * 4;         // 12.8 MB
    float* Wp     = (float*)p; p += 2 * 128 * 32 * 4;     // 32 KB padded weights

    // CSR temporaries, dead after k_p6 -> alias onto agg1 and agg2:
    int* ebuf = (int*)alias0;                             // 12.8 MB (packed 24-bit)
    int* blockCnt    = (int*)alias1;                                  // 1.23 MB
    int* blockOff    = blockCnt + (size_t)neb * nbuck;                // 1.23 MB
    int* bucketTot   = blockOff + (size_t)neb * nbuck;                // ~3 KB
    int* bucketStart = bucketTot + nbuck;                             // ~3 KB

    hipMemsetAsync(gmaxU, 0, (size_t)G * (F2 * 4 * 2 + 4), stream); // gmaxU+gsum+cnt

    // --- CSR build (no global atomics) ---
    k_p1<<<neb, 256, 0, stream>>>(ei, blockCnt, E, nbuck);
    k_p2<<<nbuck, 256, 0, stream>>>(blockCnt, blockOff, bucketTot, neb, nbuck);
    k_p3<<<1, 256, 0, stream>>>(bucketTot, bucketStart, nbuck);
    k_p4<<<neb, 256, 0, stream>>>(ei, bucketStart, blockOff, ebuf, E, nbuck);
    k_p5<<<nbuck, 256, 0, stream>>>(ebuf, bucketStart, deg, n);
    k_scan1<<<nb, 256, 0, stream>>>(deg, bsum, n);
    k_scan2<<<1, 64, 0, stream>>>(bsum, boff, nb);
    k_scan3<<<nb, 256, 0, stream>>>(deg, boff, rowstart, n);
    k_p6<<<nbuck, 256, 0, stream>>>(ebuf, bucketStart, rowstart, perm, n,
                                    qs, 2 * qs, 3 * qs);

    // --- projections + aggregations ---
    k_prepw<<<32, 256, 0, stream>>>(Wrel1, Wroot1, Wp);
    k_proj1<<<((size_t)n * 8 + 255) / 256, 256, 0, stream>>>(x, Wp, y1, r1, n);
    k_agg1<<<(n * 8 + 255) / 256, 256, 0, stream>>>(rowstart, deg, perm, y1, agg1, n);
    k_mid<<<(n + 255) / 256, 256, 0, stream>>>(agg1, r1, b1, bn1_g, bn1_b, bn1_m,
                                               bn1_v, Wrel2, Wroot2, b2, y2, r2, n);
    k_agg2<<<(n * 5 + 255) / 256, 256, 0, stream>>>(rowstart, deg, perm, y2, agg2, n);
    k_pool<<<(n + 255) / 256, 256, 0, stream>>>(agg2, r2, batch, bn2_g, bn2_b,
                                                bn2_m, bn2_v, gmaxU, gsum, cnt, n);
    k_head<<<(G + 255) / 256, 256, 0, stream>>>(gmaxU, gsum, cnt, W_lin1, b_lin1,
                                                W_lin2, b_lin2, out, G);
}

// Round 6
// 421.603 us; speedup vs baseline: 1.2200x; 1.2200x over previous
//
#include <hip/hip_runtime.h>
#include <math.h>

#define NFEAT 128
#define F1    30   // conv1 out features
#define F1P   32   // padded width for conv1 tables
#define F2    20   // conv2 out features

#define EPB     8192   // edges per block in CSR-build passes
#define MAXBUCK 1024   // LDS sizing; NBUCK = ceil(n/128) must be <= this

// ------- prep: Wp[table][k][j] padded 128x32, table 0=rel, 1=root --------------
__global__ __launch_bounds__(256) void k_prepw(
    const float* __restrict__ Wrel, const float* __restrict__ Wroot,
    float* __restrict__ Wp)
{
    int i = blockIdx.x * 256 + threadIdx.x;
    if (i >= 2 * 128 * 32) return;
    int table = i >> 12, rem = i & 4095, k = rem >> 5, j = rem & 31;
    const float* W = table ? Wroot : Wrel;
    Wp[i] = (j < F1) ? W[k * F1 + j] : 0.f;
}

// ------- k_proj1: block=512 (8 waves), 64 nodes/block. wave=(table,q) uniform ---
// x staged in LDS (XOR-swizzled float4, k4-major) so W loads stay scalar (s_load)
// and each x row is fetched from global exactly once, coalesced.
__global__ __launch_bounds__(512) void k_proj1(
    const float* __restrict__ x, const float* __restrict__ Wp,
    float* __restrict__ y1, float* __restrict__ r1, int n)
{
    __shared__ float4 xs4[2048];           // 64 rows x 32 k4, swizzled, 32 KB
    int tid = threadIdx.x;
    int base = blockIdx.x * 64;

    // stage: coalesced global read, swizzled LDS write
#pragma unroll
    for (int it = 0; it < 4; it++) {
        int idx = it * 512 + tid;
        int k4 = idx & 31, row = idx >> 5;
        int gnode = base + row;
        float4 v = make_float4(0.f, 0.f, 0.f, 0.f);
        if (gnode < n) v = ((const float4*)(x + (size_t)gnode * NFEAT))[k4];
        xs4[k4 * 64 + (row ^ k4)] = v;
    }
    __syncthreads();

    int lane = tid & 63;
    int combo = __builtin_amdgcn_readfirstlane(tid >> 6);  // 0..7, wave-uniform
    int table = combo >> 2, q = combo & 3;
    int node = base + lane;
    if (node >= n) return;

    const float* Wt = Wp + table * 4096 + q * 8;           // SGPR-derived
    float acc[8];
#pragma unroll
    for (int j = 0; j < 8; j++) acc[j] = 0.f;

    for (int k4 = 0; k4 < 32; k4++) {
        float4 xk = xs4[k4 * 64 + (lane ^ k4)];
#pragma unroll
        for (int kk = 0; kk < 4; kk++) {
            float xs = kk == 0 ? xk.x : kk == 1 ? xk.y : kk == 2 ? xk.z : xk.w;
            const float* w = Wt + (k4 * 4 + kk) * 32;      // wave-uniform -> s_load
            acc[0] += xs * w[0]; acc[1] += xs * w[1];
            acc[2] += xs * w[2]; acc[3] += xs * w[3];
            acc[4] += xs * w[4]; acc[5] += xs * w[5];
            acc[6] += xs * w[6]; acc[7] += xs * w[7];
        }
    }
    float* outp = (table ? r1 : y1) + (size_t)node * F1P + q * 8;
    ((float4*)outp)[0] = make_float4(acc[0], acc[1], acc[2], acc[3]);
    ((float4*)outp)[1] = make_float4(acc[4], acc[5], acc[6], acc[7]);
}

// ============ CSR build: hierarchical counting sort, no global atomics ==========
// p1: per-block LDS histogram over buckets (bucket = dst >> 7)
__global__ __launch_bounds__(256) void k_p1(
    const int* __restrict__ ei, int* __restrict__ blockCnt,
    int E, int nbuck)
{
    __shared__ int lh[MAXBUCK];
    int t = threadIdx.x;
    for (int i = t; i < nbuck; i += 256) lh[i] = 0;
    __syncthreads();
    const int* dst = ei + E;
    int base = blockIdx.x * EPB;
#pragma unroll 4
    for (int k = 0; k < EPB / 256; k++) {
        int e = base + k * 256 + t;
        if (e < E) atomicAdd(&lh[dst[e] >> 7], 1);
    }
    __syncthreads();
    int* out = blockCnt + (size_t)blockIdx.x * nbuck;
    for (int i = t; i < nbuck; i += 256) out[i] = lh[i];
}

// p2: per-bucket exclusive scan across edge-blocks (one workgroup per bucket)
__global__ __launch_bounds__(256) void k_p2(
    const int* __restrict__ blockCnt, int* __restrict__ blockOff,
    int* __restrict__ bucketTot, int neb, int nbuck)
{
    __shared__ int sdata[256];
    __shared__ int carry_s;
    int b = blockIdx.x;
    int t = threadIdx.x;
    if (t == 0) carry_s = 0;
    __syncthreads();
    for (int base = 0; base < neb; base += 512) {
        int i0 = base + 2 * t, i1 = i0 + 1;
        int c0 = (i0 < neb) ? blockCnt[(size_t)i0 * nbuck + b] : 0;
        int c1 = (i1 < neb) ? blockCnt[(size_t)i1 * nbuck + b] : 0;
        int s = c0 + c1;
        sdata[t] = s;
        __syncthreads();
        for (int off = 1; off < 256; off <<= 1) {
            int tmp = (t >= off) ? sdata[t - off] : 0;
            __syncthreads();
            sdata[t] += tmp;
            __syncthreads();
        }
        int ex = carry_s + sdata[t] - s;
        if (i0 < neb) blockOff[(size_t)i0 * nbuck + b] = ex;
        if (i1 < neb) blockOff[(size_t)i1 * nbuck + b] = ex + c0;
        __syncthreads();
        if (t == 255) carry_s += sdata[255];
        __syncthreads();
    }
    if (t == 0) bucketTot[b] = carry_s;
}

// p3: single-block parallel exclusive scan over bucket totals
__global__ __launch_bounds__(256) void k_p3(
    const int* __restrict__ bucketTot, int* __restrict__ bucketStart, int nbuck)
{
    __shared__ int sdata[256];
    __shared__ int carry_s;
    int t = threadIdx.x;
    if (t == 0) carry_s = 0;
    __syncthreads();
    for (int base = 0; base < nbuck; base += 1024) {
        int v[4]; int s = 0;
#pragma unroll
        for (int i = 0; i < 4; i++) {
            int idx = base + t * 4 + i;
            v[i] = (idx < nbuck) ? bucketTot[idx] : 0;
            s += v[i];
        }
        sdata[t] = s;
        __syncthreads();
        for (int off = 1; off < 256; off <<= 1) {
            int tmp = (t >= off) ? sdata[t - off] : 0;
            __syncthreads();
            sdata[t] += tmp;
            __syncthreads();
        }
        int ex = carry_s + sdata[t] - s;
#pragma unroll
        for (int i = 0; i < 4; i++) {
            int idx = base + t * 4 + i;
            if (idx < nbuck) bucketStart[idx] = ex;
            ex += v[i];
        }
        __syncthreads();
        if (t == 255) carry_s += sdata[255];
        __syncthreads();
    }
    if (t == 0) bucketStart[nbuck] = carry_s;
}

// p4: scatter edges into bucket-sorted packed (src<<7 | dst&127) via LDS cursors
__global__ __launch_bounds__(256) void k_p4(
    const int* __restrict__ ei, const int* __restrict__ bucketStart,
    const int* __restrict__ blockOff, int* __restrict__ ebuf,
    int E, int nbuck)
{
    __shared__ int cur[MAXBUCK];
    int t = threadIdx.x;
    const int* boff = blockOff + (size_t)blockIdx.x * nbuck;
    for (int i = t; i < nbuck; i += 256) cur[i] = bucketStart[i] + boff[i];
    __syncthreads();
    const int* dst = ei + E;
    int base = blockIdx.x * EPB;
#pragma unroll 4
    for (int k = 0; k < EPB / 256; k++) {
        int e = base + k * 256 + t;
        if (e < E) {
            int s = ei[e], d = dst[e];
            int p = atomicAdd(&cur[d >> 7], 1);
            ebuf[p] = (s << 7) | (d & 127);
        }
    }
}

// p5: per-bucket 128-bin node histogram -> deg (plain stores, no atomics)
__global__ __launch_bounds__(256) void k_p5(
    const int* __restrict__ ebuf, const int* __restrict__ bucketStart,
    int* __restrict__ deg, int n)
{
    __shared__ int nh[128];
    int t = threadIdx.x;
    int b = blockIdx.x;
    if (t < 128) nh[t] = 0;
    __syncthreads();
    int lo = bucketStart[b], hi = bucketStart[b + 1];
    for (int p = lo + t; p < hi; p += 256)
        atomicAdd(&nh[ebuf[p] & 127], 1);
    __syncthreads();
    if (t < 128) {
        int node = b * 128 + t;
        if (node < n) deg[node] = nh[t];
    }
}

// scan over deg -> rowstart (3 kernels, 1024-elt chunks)
__global__ __launch_bounds__(256) void k_scan1(
    const int* __restrict__ deg, int* __restrict__ bsum, int n)
{
    __shared__ int sdata[256];
    int t = threadIdx.x;
    int base = blockIdx.x * 1024;
    int s = 0;
#pragma unroll
    for (int i = 0; i < 4; i++) {
        int idx = base + t * 4 + i;
        if (idx < n) s += deg[idx];
    }
    sdata[t] = s;
    __syncthreads();
    for (int off = 128; off > 0; off >>= 1) {
        if (t < off) sdata[t] += sdata[t + off];
        __syncthreads();
    }
    if (t == 0) bsum[blockIdx.x] = sdata[0];
}

__global__ void k_scan2(const int* __restrict__ bsum, int* __restrict__ boff, int nb)
{
    if (threadIdx.x == 0 && blockIdx.x == 0) {
        int acc = 0;
        for (int i = 0; i < nb; i++) { boff[i] = acc; acc += bsum[i]; }
    }
}

__global__ __launch_bounds__(256) void k_scan3(
    const int* __restrict__ deg, const int* __restrict__ boff,
    int* __restrict__ rowstart, int n)
{
    __shared__ int sdata[256];
    int t = threadIdx.x;
    int base = blockIdx.x * 1024;
    int v[4]; int s = 0;
#pragma unroll
    for (int i = 0; i < 4; i++) {
        int idx = base + t * 4 + i;
        v[i] = (idx < n) ? deg[idx] : 0;
        s += v[i];
    }
    sdata[t] = s;
    __syncthreads();
    for (int off = 1; off < 256; off <<= 1) {
        int tmp = (t >= off) ? sdata[t - off] : 0;
        __syncthreads();
        sdata[t] += tmp;
        __syncthreads();
    }
    int ex = boff[blockIdx.x] + sdata[t] - s;
#pragma unroll
    for (int i = 0; i < 4; i++) {
        int idx = base + t * 4 + i;
        if (idx < n) rowstart[idx] = ex;
        ex += v[i];
    }
}

// p6: per-bucket scatter into perm, src-QUARTILE ordered within each node's list
__global__ __launch_bounds__(256) void k_p6(
    const int* __restrict__ ebuf, const int* __restrict__ bucketStart,
    const int* __restrict__ rowstart, int* __restrict__ perm, int n,
    int t1, int t2, int t3)
{
    __shared__ int cur[128];
    int t = threadIdx.x;
    int b = blockIdx.x;
    if (t < 128) {
        int node = b * 128 + t;
        cur[t] = (node < n) ? rowstart[node] : 0;
    }
    __syncthreads();
    int lo = bucketStart[b], hi = bucketStart[b + 1];
    for (int pass = 0; pass < 4; pass++) {
        for (int p = lo + t; p < hi; p += 256) {
            int e = ebuf[p];
            int src = e >> 7;
            int qq = (src >= t1) + (src >= t2) + (src >= t3);
            if (qq == pass) {
                int q = atomicAdd(&cur[e & 127], 1);
                perm[q] = src;
            }
        }
        __syncthreads();   // phase coherence across the block
    }
}

// ---------------- gather-sum aggregations (no atomics, unroll-4) ----------------
__global__ __launch_bounds__(256) void k_agg1(
    const int* __restrict__ rowstart, const int* __restrict__ deg,
    const int* __restrict__ perm, const float* __restrict__ y1,
    float* __restrict__ agg1, int n)
{
    int idx = blockIdx.x * 256 + threadIdx.x;
    int node = idx >> 3, q = idx & 7;
    if (node >= n) return;
    int s = rowstart[node], e = s + deg[node];
    float4 acc = {0.f, 0.f, 0.f, 0.f};
    int j = s;
    for (; j + 4 <= e; j += 4) {
        int s0 = perm[j], s1 = perm[j + 1], s2 = perm[j + 2], s3 = perm[j + 3];
        float4 v0 = *(const float4*)(y1 + (size_t)s0 * F1P + q * 4);
        float4 v1 = *(const float4*)(y1 + (size_t)s1 * F1P + q * 4);
        float4 v2 = *(const float4*)(y1 + (size_t)s2 * F1P + q * 4);
        float4 v3 = *(const float4*)(y1 + (size_t)s3 * F1P + q * 4);
        acc.x += v0.x; acc.y += v0.y; acc.z += v0.z; acc.w += v0.w;
        acc.x += v1.x; acc.y += v1.y; acc.z += v1.z; acc.w += v1.w;
        acc.x += v2.x; acc.y += v2.y; acc.z += v2.z; acc.w += v2.w;
        acc.x += v3.x; acc.y += v3.y; acc.z += v3.z; acc.w += v3.w;
    }
    for (; j < e; j++) {
        int sr = perm[j];
        float4 v = *(const float4*)(y1 + (size_t)sr * F1P + q * 4);
        acc.x += v.x; acc.y += v.y; acc.z += v.z; acc.w += v.w;
    }
    *(float4*)(agg1 + (size_t)node * F1P + q * 4) = acc;
}

__global__ __launch_bounds__(256) void k_agg2(
    const int* __restrict__ rowstart, const int* __restrict__ deg,
    const int* __restrict__ perm, const float* __restrict__ y2,
    float* __restrict__ agg2, int n)
{
    int idx = blockIdx.x * 256 + threadIdx.x;
    int node = idx / 5, q = idx - node * 5;
    if (node >= n) return;
    int s = rowstart[node], e = s + deg[node];
    float4 acc = {0.f, 0.f, 0.f, 0.f};
    int j = s;
    for (; j + 4 <= e; j += 4) {
        int s0 = perm[j], s1 = perm[j + 1], s2 = perm[j + 2], s3 = perm[j + 3];
        float4 v0 = *(const float4*)(y2 + (size_t)s0 * F2 + q * 4);
        float4 v1 = *(const float4*)(y2 + (size_t)s1 * F2 + q * 4);
        float4 v2 = *(const float4*)(y2 + (size_t)s2 * F2 + q * 4);
        float4 v3 = *(const float4*)(y2 + (size_t)s3 * F2 + q * 4);
        acc.x += v0.x; acc.y += v0.y; acc.z += v0.z; acc.w += v0.w;
        acc.x += v1.x; acc.y += v1.y; acc.z += v1.z; acc.w += v1.w;
        acc.x += v2.x; acc.y += v2.y; acc.z += v2.z; acc.w += v2.w;
        acc.x += v3.x; acc.y += v3.y; acc.z += v3.z; acc.w += v3.w;
    }
    for (; j < e; j++) {
        int sr = perm[j];
        float4 v = *(const float4*)(y2 + (size_t)sr * F2 + q * 4);
        acc.x += v.x; acc.y += v.y; acc.z += v.z; acc.w += v.w;
    }
    *(float4*)(agg2 + (size_t)node * F2 + q * 4) = acc;
}

// ---------------- k_mid: h = bn1(relu(agg1+r1+b1)); y2=h@Wrel2; r2=h@Wroot2+b2 --
__global__ __launch_bounds__(256) void k_mid(
    const float* __restrict__ agg1, const float* __restrict__ r1,
    const float* __restrict__ b1,
    const float* __restrict__ g1, const float* __restrict__ bb1,
    const float* __restrict__ m1, const float* __restrict__ v1,
    const float* __restrict__ Wrel2, const float* __restrict__ Wroot2,
    const float* __restrict__ b2,
    float* __restrict__ y2, float* __restrict__ r2, int n)
{
    int node = blockIdx.x * 256 + threadIdx.x;
    if (node >= n) return;
    float h[F1];
    const float4* av = (const float4*)(agg1 + (size_t)node * F1P);
    const float4* rv = (const float4*)(r1   + (size_t)node * F1P);
#pragma unroll
    for (int q = 0; q < 8; q++) {
        float4 a = av[q], r = rv[q];
        int j = q * 4;
        if (j + 0 < F1) h[j + 0] = a.x + r.x;
        if (j + 1 < F1) h[j + 1] = a.y + r.y;
        if (j + 2 < F1) h[j + 2] = a.z + r.z;
        if (j + 3 < F1) h[j + 3] = a.w + r.w;
    }
#pragma unroll
    for (int j = 0; j < F1; j++) {
        float t = fmaxf(h[j] + b1[j], 0.f);
        float sc = g1[j] / sqrtf(v1[j] + 1e-5f);
        h[j] = (t - m1[j]) * sc + bb1[j];
    }
    float ay[F2], ar[F2];
#pragma unroll
    for (int j = 0; j < F2; j++) { ay[j] = 0.f; ar[j] = b2[j]; }
    for (int k = 0; k < F1; k++) {
        float hk = h[k];
#pragma unroll
        for (int j = 0; j < F2; j++) {
            ay[j] += hk * Wrel2 [k * F2 + j];
            ar[j] += hk * Wroot2[k * F2 + j];
        }
    }
    float4* yo = (float4*)(y2 + (size_t)node * F2);
    float4* ro = (float4*)(r2 + (size_t)node * F2);
#pragma unroll
    for (int q = 0; q < 5; q++) {
        float4 vy, vr;
        vy.x = ay[q*4+0]; vy.y = ay[q*4+1]; vy.z = ay[q*4+2]; vy.w = ay[q*4+3];
        vr.x = ar[q*4+0]; vr.y = ar[q*4+1]; vr.z = ar[q*4+2]; vr.w = ar[q*4+3];
        yo[q] = vy;  ro[q] = vr;
    }
}

// ------------- k_pool: segmented (batch sorted) pool, flush-on-change -----------
__global__ __launch_bounds__(256) void k_pool(
    const float* __restrict__ agg2, const float* __restrict__ r2,
    const int* __restrict__ batch,
    const float* __restrict__ g2, const float* __restrict__ bb2,
    const float* __restrict__ m2, const float* __restrict__ v2,
    unsigned* __restrict__ gmaxU, float* __restrict__ gsum,
    int* __restrict__ cnt, int n)
{
    int t = threadIdx.x;
    if (t >= 240) return;                 // 12 subsets x 20 features
    int i = t / 20, j = t - (t / 20) * 20;
    int base = blockIdx.x * 256;
    int nend = min(base + 256, n);
    float sc = g2[j] / sqrtf(v2[j] + 1e-5f);
    float mj = m2[j], bj = bb2[j];

    int curg = -1, c = 0;
    float mx = -3.4e38f, sm = 0.f;
    for (int node = base + i; node < nend; node += 12) {
        int g = batch[node];
        if (g != curg) {
            if (curg >= 0) {
                atomicAdd(&gsum[curg * F2 + j], sm);
                unsigned bits = __float_as_uint(mx);
                unsigned mapped = (bits & 0x80000000u) ? ~bits : (bits | 0x80000000u);
                atomicMax(&gmaxU[curg * F2 + j], mapped);
                if (j == 0) atomicAdd(&cnt[curg], c);
            }
            curg = g; c = 0; mx = -3.4e38f; sm = 0.f;
        }
        float a = agg2[(size_t)node * F2 + j] + r2[(size_t)node * F2 + j];
        a = fmaxf(a, 0.f);                 // b2 folded into r2
        float h2 = (a - mj) * sc + bj;
        mx = fmaxf(mx, h2); sm += h2; c++;
    }
    if (curg >= 0) {
        atomicAdd(&gsum[curg * F2 + j], sm);
        unsigned bits = __float_as_uint(mx);
        unsigned mapped = (bits & 0x80000000u) ? ~bits : (bits | 0x80000000u);
        atomicMax(&gmaxU[curg * F2 + j], mapped);
        if (j == 0) atomicAdd(&cnt[curg], c);
    }
}

// ---------------- Kernel F: head MLP + sigmoid ---------------------------------
__global__ __launch_bounds__(256) void k_head(
    const unsigned* __restrict__ gmaxU, const float* __restrict__ gsum,
    const int* __restrict__ cnt,
    const float* __restrict__ W1, const float* __restrict__ b1h,
    const float* __restrict__ W2, const float* __restrict__ b2h,
    float* __restrict__ out, int G)
{
    int g = blockIdx.x * 256 + threadIdx.x;
    if (g >= G) return;
    int c = cnt[g];
    float cf = fmaxf((float)c, 1.f);
    float z[2 * F2];
#pragma unroll
    for (int j = 0; j < F2; j++) {
        unsigned u = gmaxU[g * F2 + j];
        float gm = 0.f;
        if (c != 0) {
            gm = (u & 0x80000000u) ? __uint_as_float(u & 0x7FFFFFFFu)
                                   : __uint_as_float(~u);
            if (!isfinite(gm)) gm = 0.f;
        }
        z[j]      = gm;
        z[F2 + j] = gsum[g * F2 + j] / cf;
    }
    float a[10];
#pragma unroll
    for (int i = 0; i < 10; i++) a[i] = b1h[i];
    for (int k = 0; k < 2 * F2; k++) {
        float zk = z[k];
#pragma unroll
        for (int i = 0; i < 10; i++) a[i] += zk * W1[k * 10 + i];
    }
    float o = b2h[0];
#pragma unroll
    for (int i = 0; i < 10; i++) o += fmaxf(a[i], 0.f) * W2[i];
    out[g] = 1.f / (1.f + expf(-o));
}

// ---------------- launch --------------------------------------------------------
extern "C" void kernel_launch(void* const* d_in, const int* in_sizes, int n_in,
                              void* d_out, int out_size, void* d_ws, size_t ws_size,
                              hipStream_t stream)
{
    const float* x      = (const float*)d_in[0];
    const int*   ei     = (const int*)  d_in[1];
    const int*   batch  = (const int*)  d_in[2];
    const float* Wrel1  = (const float*)d_in[3];
    const float* Wroot1 = (const float*)d_in[4];
    const float* b1     = (const float*)d_in[5];
    const float* bn1_g  = (const float*)d_in[6];
    const float* bn1_b  = (const float*)d_in[7];
    const float* bn1_m  = (const float*)d_in[8];
    const float* bn1_v  = (const float*)d_in[9];
    const float* Wrel2  = (const float*)d_in[10];
    const float* Wroot2 = (const float*)d_in[11];
    const float* b2     = (const float*)d_in[12];
    const float* bn2_g  = (const float*)d_in[13];
    const float* bn2_b  = (const float*)d_in[14];
    const float* bn2_m  = (const float*)d_in[15];
    const float* bn2_v  = (const float*)d_in[16];
    const float* W_lin1 = (const float*)d_in[17];
    const float* b_lin1 = (const float*)d_in[18];
    const float* W_lin2 = (const float*)d_in[19];
    const float* b_lin2 = (const float*)d_in[20];
    float* out = (float*)d_out;

    int n = in_sizes[0] / NFEAT;     // 100000
    int E = in_sizes[1] / 2;         // 3200000
    int G = out_size;                // 512
    int nb = (n + 1023) / 1024;      // scan chunks over nodes
    int nbuck = (n + 127) >> 7;      // 782 buckets of 128 nodes
    int neb = (E + EPB - 1) / EPB;   // 391 edge blocks
    int qs = (n + 3) >> 2;           // src quartile size

    char* p = (char*)d_ws;
    float* y1   = (float*)p;  p += (size_t)n * F1P * 4;   // 12.8 MB
    float* r1   = (float*)p;  p += (size_t)n * F1P * 4;   // 12.8 MB
    char* alias0 = p;                                     // start of aliased region
    float* agg1 = (float*)p;  p += (size_t)n * F1P * 4;   // 12.8 MB
    float* y2   = (float*)p;  p += (size_t)n * F2 * 4;    // 8 MB
    float* r2   = (float*)p;  p += (size_t)n * F2 * 4;    // 8 MB
    char* alias1 = p;                                     // start of 2nd alias region
    float* agg2 = (float*)p;  p += (size_t)n * F2 * 4;    // 8 MB
    unsigned* gmaxU = (unsigned*)p;  p += (size_t)G * F2 * 4;
    float*    gsum  = (float*)p;     p += (size_t)G * F2 * 4;
    int*      cnt   = (int*)p;       p += (size_t)G * 4;
    int* deg      = (int*)p;  p += (size_t)n * 4;
    int* rowstart = (int*)p;  p += (size_t)n * 4;
    int* bsum     = (int*)p;  p += (size_t)nb * 4;
    int* boff     = (int*)p;  p += (size_t)nb * 4;
    int* perm     = (int*)p;  p += (size_t)E * 4;         // 12.8 MB
    float* Wp     = (float*)p; p += 2 * 128 * 32 * 4;     // 32 KB padded weights

    // CSR temporaries, dead after k_p6 -> alias onto agg1 and agg2:
    int* ebuf = (int*)alias0;                             // 12.8 MB (packed 24-bit)
    int* blockCnt    = (int*)alias1;                                  // 1.23 MB
    int* blockOff    = blockCnt + (size_t)neb * nbuck;                // 1.23 MB
    int* bucketTot   = blockOff + (size_t)neb * nbuck;                // ~3 KB
    int* bucketStart = bucketTot + nbuck;                             // ~3 KB

    hipMemsetAsync(gmaxU, 0, (size_t)G * (F2 * 4 * 2 + 4), stream); // gmaxU+gsum+cnt

    // --- CSR build (no global atomics) ---
    k_p1<<<neb, 256, 0, stream>>>(ei, blockCnt, E, nbuck);
    k_p2<<<nbuck, 256, 0, stream>>>(blockCnt, blockOff, bucketTot, neb, nbuck);
    k_p3<<<1, 256, 0, stream>>>(bucketTot, bucketStart, nbuck);
    k_p4<<<neb, 256, 0, stream>>>(ei, bucketStart, blockOff, ebuf, E, nbuck);
    k_p5<<<nbuck, 256, 0, stream>>>(ebuf, bucketStart, deg, n);
    k_scan1<<<nb, 256, 0, stream>>>(deg, bsum, n);
    k_scan2<<<1, 64, 0, stream>>>(bsum, boff, nb);
    k_scan3<<<nb, 256, 0, stream>>>(deg, boff, rowstart, n);
    k_p6<<<nbuck, 256, 0, stream>>>(ebuf, bucketStart, rowstart, perm, n,
                                    qs, 2 * qs, 3 * qs);

    // --- projections + aggregations ---
    k_prepw<<<32, 256, 0, stream>>>(Wrel1, Wroot1, Wp);
    k_proj1<<<(n + 63) / 64, 512, 0, stream>>>(x, Wp, y1, r1, n);
    k_agg1<<<(n * 8 + 255) / 256, 256, 0, stream>>>(rowstart, deg, perm, y1, agg1, n);
    k_mid<<<(n + 255) / 256, 256, 0, stream>>>(agg1, r1, b1, bn1_g, bn1_b, bn1_m,
                                               bn1_v, Wrel2, Wroot2, b2, y2, r2, n);
    k_agg2<<<(n * 5 + 255) / 256, 256, 0, stream>>>(rowstart, deg, perm, y2, agg2, n);
    k_pool<<<(n + 255) / 256, 256, 0, stream>>>(agg2, r2, batch, bn2_g, bn2_b,
                                                bn2_m, bn2_v, gmaxU, gsum, cnt, n);
    k_head<<<(G + 255) / 256, 256, 0, stream>>>(gmaxU, gsum, cnt, W_lin1, b_lin1,
                                                W_lin2, b_lin2, out, G);
}